// Round 4
// baseline (514.903 us; speedup 1.0000x reference)
//
#include <hip/hip_runtime.h>
#include <math.h>

#define WF 64

__device__ __forceinline__ float silu_f(float v){ return v / (1.0f + expf(-v)); }

// ---------- CSR build ----------
__global__ __launch_bounds__(256) void k_count(const int* __restrict__ dst, int* __restrict__ cnt, int E){
  int e = blockIdx.x*blockDim.x + threadIdx.x;
  if (e < E) atomicAdd(&cnt[dst[e]], 1);
}

// block-local exclusive scan over chunks of 2048 (256 thr x 8 items)
__global__ __launch_bounds__(256) void k_scan1(const int* __restrict__ cnt, int* __restrict__ rowstart, int* __restrict__ bsum, int N){
  __shared__ int s[256];
  int tid = threadIdx.x;
  int base = blockIdx.x*2048 + tid*8;
  int loc[8]; int tsum = 0;
#pragma unroll
  for (int j=0;j<8;++j){ int idx=base+j; int v = (idx<N)?cnt[idx]:0; loc[j]=tsum; tsum+=v; }
  s[tid]=tsum; __syncthreads();
  for (int off=1; off<256; off<<=1){
    int v = (tid>=off)? s[tid-off] : 0;
    __syncthreads();
    s[tid] += v;
    __syncthreads();
  }
  int texc = s[tid] - tsum;
  if (tid==255) bsum[blockIdx.x] = s[255];
#pragma unroll
  for (int j=0;j<8;++j){ int idx=base+j; if (idx<N) rowstart[idx] = texc + loc[j]; }
}

// scan3: adds block prefix (computed in-kernel from bsum), writes cursor/dinv
__global__ __launch_bounds__(256) void k_scan3(const int* __restrict__ bsum, const int* __restrict__ cnt,
                        int* __restrict__ rowstart, int* __restrict__ cursor,
                        float* __restrict__ dinv, int N, int E, int nb){
  __shared__ int boffs;
  int tid = threadIdx.x;
  int b = (blockIdx.x*blockDim.x) >> 11;   // uniform within block (256 <= 2048)
  if (tid < WF){
    int v = (tid < nb && tid < b) ? bsum[tid] : 0;
#pragma unroll
    for (int off=32; off; off>>=1) v += __shfl_down(v, off);
    if (tid==0) boffs = v;
  }
  __syncthreads();
  int idx = blockIdx.x*blockDim.x + tid;
  if (idx < N){
    int v = rowstart[idx] + boffs;
    rowstart[idx]=v; cursor[idx]=v;
    dinv[idx] = rsqrtf((float)(cnt[idx]+1));   // +1 self-loop
  }
  if (idx==0) rowstart[N]=E;
}

__global__ __launch_bounds__(256) void k_fill(const int* __restrict__ src, const int* __restrict__ dst,
                       const float* __restrict__ dinv, int* __restrict__ cursor,
                       int* __restrict__ colsrc, float* __restrict__ wedge, int E){
  int e = blockIdx.x*blockDim.x + threadIdx.x;
  if (e < E){
    int d = dst[e], s = src[e];
    int pos = atomicAdd(&cursor[d], 1);
    colsrc[pos] = s;
    wedge[pos] = dinv[s];
  }
}

// ---------- layer 1: aggregate x (3 feats) then x W1 + b1, silu ----------
__global__ __launch_bounds__(256) void k_l1(const float* __restrict__ x, const int* __restrict__ rowstart,
                     const int* __restrict__ colsrc, const float* __restrict__ wedge,
                     const float* __restrict__ dinv, const float* __restrict__ W1,
                     const float* __restrict__ b1, float* __restrict__ h1s, int N){
  __shared__ float w[300];
  __shared__ float bb[100];
  int tid = threadIdx.x;
  for (int t=tid; t<300; t+=blockDim.x) w[t]=W1[t];
  for (int t=tid; t<100; t+=blockDim.x) bb[t]=b1[t];
  __syncthreads();
  int i = blockIdx.x*blockDim.x + tid;
  if (i >= N) return;
  float di = dinv[i];
  float sx = di*x[3*i+0], sy = di*x[3*i+1], sz = di*x[3*i+2];  // self-loop term
  int jb = rowstart[i], je = rowstart[i+1];
  for (int j=jb; j<je; ++j){
    int u = colsrc[j]; float wv = wedge[j];
    sx += wv*x[3*u+0]; sy += wv*x[3*u+1]; sz += wv*x[3*u+2];
  }
  sx*=di; sy*=di; sz*=di;
  float* orow = h1s + (size_t)i*100;
#pragma unroll
  for (int f0=0; f0<100; f0+=4){
    float4 o;
    o.x = silu_f(sx*w[f0+0] + sy*w[100+f0+0] + sz*w[200+f0+0] + bb[f0+0]);
    o.y = silu_f(sx*w[f0+1] + sy*w[100+f0+1] + sz*w[200+f0+1] + bb[f0+1]);
    o.z = silu_f(sx*w[f0+2] + sy*w[100+f0+2] + sz*w[200+f0+2] + bb[f0+2]);
    o.w = silu_f(sx*w[f0+3] + sy*w[100+f0+3] + sz*w[200+f0+3] + bb[f0+3]);
    *(float4*)&orow[f0] = o;
  }
}

// ---------- layer 2 aggregation: a2 = A_norm h1s  (100 feats) ----------
// one WAVE per node; lanes 0..49 each own 2 features (float2)
__global__ __launch_bounds__(256) void k_agg2(const float* __restrict__ h1s, const int* __restrict__ rowstart,
                       const int* __restrict__ colsrc, const float* __restrict__ wedge,
                       const float* __restrict__ dinv, float* __restrict__ a2, int N){
  int node = blockIdx.x*4 + (threadIdx.x >> 6);
  int lane = threadIdx.x & 63;
  if (node >= N || lane >= 50) return;
  float di = dinv[node];
  const float* selfrow = h1s + (size_t)node*100 + 2*lane;
  float2 v = *(const float2*)selfrow;
  float ax = di*v.x, ay = di*v.y;
  int jb = rowstart[node], je = rowstart[node+1];
  for (int j=jb; j<je; ++j){
    int u = colsrc[j]; float wv = wedge[j];
    float2 r = *(const float2*)(h1s + (size_t)u*100 + 2*lane);
    ax += wv*r.x; ay += wv*r.y;
  }
  float2 o; o.x = di*ax; o.y = di*ay;
  *(float2*)(a2 + (size_t)node*100 + 2*lane) = o;
}

// ---------- layer 2 matmul: h2s = silu(a2 @ W2 + b2), [N,100]x[100,200] ----------
// block = 1 wave (64 thr). tile 64n x 200f. micro-tile 8n x 25f.
// tid = ng*8 + fg ; fg in [0,8) owns f-slice fg*25..+25 ; node set {ng+8i}.
// aS[64][102] natural layout (pad 102: conflict-free scalar col reads).
// wT[25][8][28] per 25-k tile (per-group 28-pad -> aligned b128, banks exact-cover).
#define KSTEP 25
#define WPAD 28
__global__ __launch_bounds__(64, 1) void k_mm2(const float* __restrict__ a2, const float* __restrict__ W2,
                      const float* __restrict__ b2, float* __restrict__ h2s, int N){
  __shared__ float aS[64][102];
  __shared__ float wT[KSTEP][8*WPAD];
  int tid = threadIdx.x;
  int fg = tid & 7;     // 8 f-groups x 25
  int ng = tid >> 3;    // 8 node-groups; nodes ng+8i
  int n0 = blockIdx.x * 64;

  // stage A tile once: 64 rows x 50 float2, coalesced, linear
  for (int idx = tid; idx < 64*50; idx += 64){
    int n  = idx / 50;
    int k2 = idx - n*50;
    int gn = n0 + n;
    float2 v = (gn < N) ? *(const float2*)(a2 + (size_t)gn*100 + 2*k2)
                        : make_float2(0.f, 0.f);
    *(float2*)&aS[n][2*k2] = v;
  }

  float acc[8][25];
#pragma unroll
  for (int i=0;i<8;++i)
#pragma unroll
    for (int j=0;j<25;++j) acc[i][j]=0.f;

  for (int kt=0; kt<100; kt+=KSTEP){
    // stage W tile [25][8*28]: k outer (no div for k), f = c*64+tid
    for (int k=0; k<KSTEP; ++k){
      const float* wsrc = W2 + (size_t)(kt+k)*200;
#pragma unroll
      for (int c=0; c<4; ++c){
        int f = c*64 + tid;
        if (f < 200){
          int g = f / 25;
          int j = f - g*25;
          wT[k][g*WPAD + j] = wsrc[f];
        }
      }
    }
    __syncthreads();
#pragma unroll 2
    for (int k=0; k<KSTEP; ++k){
      int ka = kt + k;
      float a[8];
#pragma unroll
      for (int i=0;i<8;++i) a[i] = aS[ng + 8*i][ka];
      float w[25];
      const float* wr = &wT[k][fg*WPAD];
      *(float4*)&w[0]  = *(const float4*)&wr[0];
      *(float4*)&w[4]  = *(const float4*)&wr[4];
      *(float4*)&w[8]  = *(const float4*)&wr[8];
      *(float4*)&w[12] = *(const float4*)&wr[12];
      *(float4*)&w[16] = *(const float4*)&wr[16];
      *(float4*)&w[20] = *(const float4*)&wr[20];
      w[24] = wr[24];
#pragma unroll
      for (int j=0;j<25;++j){
        float wv = w[j];
#pragma unroll
        for (int i=0;i<8;++i) acc[i][j] += a[i]*wv;
      }
    }
    __syncthreads();
  }

  int fbase = fg*25;
#pragma unroll
  for (int i=0;i<8;++i){
    int n = n0 + ng + 8*i;
    if (n < N){
      float* orow = h2s + (size_t)n*200 + fbase;
#pragma unroll
      for (int j=0;j<25;++j) orow[j] = silu_f(acc[i][j] + b2[fbase+j]);
    }
  }
}

// ---------- pool (mean over batch) + MLP head, one block per graph ----------
__global__ __launch_bounds__(256) void k_pool(const float* __restrict__ h2s, const int* __restrict__ batch,
                       const float* __restrict__ W3, const float* __restrict__ b3,
                       const float* __restrict__ W4, const float* __restrict__ b4,
                       float* __restrict__ out, int N){
  __shared__ float pl[200];
  __shared__ float h3[100];
  int g = blockIdx.x; int tid = threadIdx.x;
  // lower_bound(batch, g) and lower_bound(batch, g+1)
  int lo=0, hi=N;
  while (lo<hi){ int m=(lo+hi)>>1; if (batch[m] < g) lo=m+1; else hi=m; }
  int s = lo;
  hi=N;
  while (lo<hi){ int m=(lo+hi)>>1; if (batch[m] < g+1) lo=m+1; else hi=m; }
  int e = lo;
  float inv = (e>s) ? 1.0f/(float)(e-s) : 0.0f;
  if (tid < 200){
    float acc=0.f;
    for (int n=s; n<e; ++n) acc += h2s[(size_t)n*200 + tid];
    pl[tid] = acc*inv;
  }
  __syncthreads();
  if (tid < 100){
    float acc = b3[tid];
    for (int k=0;k<200;++k) acc += pl[k]*W3[k*100+tid];
    h3[tid] = silu_f(acc);
  }
  __syncthreads();
  if (tid < WF){
    float p = 0.f;
    if (tid < 100)      p  = h3[tid]     * W4[tid];
    if (tid + 64 < 100) p += h3[tid+64]  * W4[tid+64];
#pragma unroll
    for (int off=32; off; off>>=1) p += __shfl_down(p, off);
    if (tid==0) out[g] = p + b4[0];
  }
}

extern "C" void kernel_launch(void* const* d_in, const int* in_sizes, int n_in,
                              void* d_out, int out_size, void* d_ws, size_t ws_size,
                              hipStream_t stream){
  const float* x  = (const float*)d_in[0];
  const int*   ei = (const int*)  d_in[1];
  const int* batch= (const int*)  d_in[2];
  const float* W1 = (const float*)d_in[4];
  const float* b1 = (const float*)d_in[5];
  const float* W2 = (const float*)d_in[6];
  const float* b2 = (const float*)d_in[7];
  const float* W3 = (const float*)d_in[8];
  const float* b3 = (const float*)d_in[9];
  const float* W4 = (const float*)d_in[10];
  const float* b4 = (const float*)d_in[11];
  float* out = (float*)d_out;

  int N = in_sizes[0]/3;
  int E = in_sizes[1]/2;
  int G = out_size;
  const int* src = ei;
  const int* dst = ei + E;

  char* base = (char*)d_ws; size_t off = 0;
  auto alloc = [&](size_t bytes)->void*{
    void* p = base + off;
    off = (off + bytes + 255) & ~(size_t)255;
    return p;
  };
  int*   cnt      = (int*)  alloc((size_t)N*4);
  int*   rowstart = (int*)  alloc((size_t)(N+1)*4);
  int*   cursor   = (int*)  alloc((size_t)N*4);
  int*   bsum     = (int*)  alloc(4096);
  int*   colsrc   = (int*)  alloc((size_t)E*4);
  float* wedge    = (float*)alloc((size_t)E*4);
  float* dinv     = (float*)alloc((size_t)N*4);
  float* h1s      = (float*)alloc((size_t)N*100*4);
  float* a2       = (float*)alloc((size_t)N*100*4);
  float* h2s      = (float*)alloc((size_t)N*200*4);
  (void)ws_size; (void)n_in;

  hipMemsetAsync(cnt, 0, (size_t)N*4, stream);
  int gE = (E+255)/256;
  k_count<<<gE,256,0,stream>>>(dst, cnt, E);
  int nb = (N+2047)/2048;
  k_scan1<<<nb,256,0,stream>>>(cnt, rowstart, bsum, N);
  k_scan3<<<(N+255)/256,256,0,stream>>>(bsum, cnt, rowstart, cursor, dinv, N, E, nb);
  k_fill<<<gE,256,0,stream>>>(src, dst, dinv, cursor, colsrc, wedge, E);
  k_l1<<<(N+255)/256,256,0,stream>>>(x, rowstart, colsrc, wedge, dinv, W1, b1, h1s, N);
  k_agg2<<<(N+3)/4,256,0,stream>>>(h1s, rowstart, colsrc, wedge, dinv, a2, N);
  k_mm2<<<(N+63)/64,64,0,stream>>>(a2, W2, b2, h2s, N);
  k_pool<<<G,256,0,stream>>>(h2s, batch, W3, b3, W4, b4, out, N);
}

// Round 5
// 218.841 us; speedup vs baseline: 2.3529x; 2.3529x over previous
//
#include <hip/hip_runtime.h>
#include <math.h>

#define WF 64

__device__ __forceinline__ float silu_f(float v){ return v / (1.0f + expf(-v)); }

// ---------- CSR build ----------
__global__ __launch_bounds__(256) void k_count(const int* __restrict__ dst, int* __restrict__ cnt, int E){
  int e = blockIdx.x*blockDim.x + threadIdx.x;
  if (e < E) atomicAdd(&cnt[dst[e]], 1);
}

// block-local exclusive scan over chunks of 2048 (256 thr x 8 items)
__global__ __launch_bounds__(256) void k_scan1(const int* __restrict__ cnt, int* __restrict__ rowstart, int* __restrict__ bsum, int N){
  __shared__ int s[256];
  int tid = threadIdx.x;
  int base = blockIdx.x*2048 + tid*8;
  int loc[8]; int tsum = 0;
#pragma unroll
  for (int j=0;j<8;++j){ int idx=base+j; int v = (idx<N)?cnt[idx]:0; loc[j]=tsum; tsum+=v; }
  s[tid]=tsum; __syncthreads();
  for (int off=1; off<256; off<<=1){
    int v = (tid>=off)? s[tid-off] : 0;
    __syncthreads();
    s[tid] += v;
    __syncthreads();
  }
  int texc = s[tid] - tsum;
  if (tid==255) bsum[blockIdx.x] = s[255];
#pragma unroll
  for (int j=0;j<8;++j){ int idx=base+j; if (idx<N) rowstart[idx] = texc + loc[j]; }
}

// scan3: adds block prefix (computed in-kernel from bsum), writes cursor/dinv
__global__ __launch_bounds__(256) void k_scan3(const int* __restrict__ bsum, const int* __restrict__ cnt,
                        int* __restrict__ rowstart, int* __restrict__ cursor,
                        float* __restrict__ dinv, int N, int E, int nb){
  __shared__ int boffs;
  int tid = threadIdx.x;
  int b = (blockIdx.x*blockDim.x) >> 11;   // uniform within block (256 <= 2048)
  if (tid < WF){
    int v = (tid < nb && tid < b) ? bsum[tid] : 0;
#pragma unroll
    for (int off=32; off; off>>=1) v += __shfl_down(v, off);
    if (tid==0) boffs = v;
  }
  __syncthreads();
  int idx = blockIdx.x*blockDim.x + tid;
  if (idx < N){
    int v = rowstart[idx] + boffs;
    rowstart[idx]=v; cursor[idx]=v;
    dinv[idx] = rsqrtf((float)(cnt[idx]+1));   // +1 self-loop
  }
  if (idx==0) rowstart[N]=E;
}

__global__ __launch_bounds__(256) void k_fill(const int* __restrict__ src, const int* __restrict__ dst,
                       const float* __restrict__ dinv, int* __restrict__ cursor,
                       int* __restrict__ colsrc, float* __restrict__ wedge, int E){
  int e = blockIdx.x*blockDim.x + threadIdx.x;
  if (e < E){
    int d = dst[e], s = src[e];
    int pos = atomicAdd(&cursor[d], 1);
    colsrc[pos] = s;
    wedge[pos] = dinv[s];
  }
}

// ---------- layer 1: aggregate x (3 feats) then x W1 + b1, silu ----------
__global__ __launch_bounds__(256) void k_l1(const float* __restrict__ x, const int* __restrict__ rowstart,
                     const int* __restrict__ colsrc, const float* __restrict__ wedge,
                     const float* __restrict__ dinv, const float* __restrict__ W1,
                     const float* __restrict__ b1, float* __restrict__ h1s, int N){
  __shared__ float w[300];
  __shared__ float bb[100];
  int tid = threadIdx.x;
  for (int t=tid; t<300; t+=blockDim.x) w[t]=W1[t];
  for (int t=tid; t<100; t+=blockDim.x) bb[t]=b1[t];
  __syncthreads();
  int i = blockIdx.x*blockDim.x + tid;
  if (i >= N) return;
  float di = dinv[i];
  float sx = di*x[3*i+0], sy = di*x[3*i+1], sz = di*x[3*i+2];  // self-loop term
  int jb = rowstart[i], je = rowstart[i+1];
  for (int j=jb; j<je; ++j){
    int u = colsrc[j]; float wv = wedge[j];
    sx += wv*x[3*u+0]; sy += wv*x[3*u+1]; sz += wv*x[3*u+2];
  }
  sx*=di; sy*=di; sz*=di;
  float* orow = h1s + (size_t)i*100;
#pragma unroll
  for (int f0=0; f0<100; f0+=4){
    float4 o;
    o.x = silu_f(sx*w[f0+0] + sy*w[100+f0+0] + sz*w[200+f0+0] + bb[f0+0]);
    o.y = silu_f(sx*w[f0+1] + sy*w[100+f0+1] + sz*w[200+f0+1] + bb[f0+1]);
    o.z = silu_f(sx*w[f0+2] + sy*w[100+f0+2] + sz*w[200+f0+2] + bb[f0+2]);
    o.w = silu_f(sx*w[f0+3] + sy*w[100+f0+3] + sz*w[200+f0+3] + bb[f0+3]);
    *(float4*)&orow[f0] = o;
  }
}

// ---------- layer 2 aggregation: a2 = A_norm h1s  (100 feats) ----------
// one WAVE per node; lanes 0..49 each own 2 features (float2)
__global__ __launch_bounds__(256) void k_agg2(const float* __restrict__ h1s, const int* __restrict__ rowstart,
                       const int* __restrict__ colsrc, const float* __restrict__ wedge,
                       const float* __restrict__ dinv, float* __restrict__ a2, int N){
  int node = blockIdx.x*4 + (threadIdx.x >> 6);
  int lane = threadIdx.x & 63;
  if (node >= N || lane >= 50) return;
  float di = dinv[node];
  const float* selfrow = h1s + (size_t)node*100 + 2*lane;
  float2 v = *(const float2*)selfrow;
  float ax = di*v.x, ay = di*v.y;
  int jb = rowstart[node], je = rowstart[node+1];
  for (int j=jb; j<je; ++j){
    int u = colsrc[j]; float wv = wedge[j];
    float2 r = *(const float2*)(h1s + (size_t)u*100 + 2*lane);
    ax += wv*r.x; ay += wv*r.y;
  }
  float2 o; o.x = di*ax; o.y = di*ay;
  *(float2*)(a2 + (size_t)node*100 + 2*lane) = o;
}

// ---------- layer 2 matmul: h2s = silu(a2 @ W2 + b2), [N,100]x[100,200] ----------
// grid (ceil(N/256), 5). block 256 thr (4 waves). tile 256n x 40f.
// thread: fg = tid&3 (10 f each), ng = tid>>2 (4 consecutive nodes each).
// micro-tile 4n x 10f -> acc 40 regs. A transposed in LDS per 20-k chunk;
// W tile [100][4 groups x 12 pad] staged once (aligned b128/b64 reads).
__global__ __launch_bounds__(256, 2) void k_mm2(const float* __restrict__ a2, const float* __restrict__ W2,
                      const float* __restrict__ b2, float* __restrict__ h2s, int N){
  __shared__ float aS[20][260];   // aS[kl][n]
  __shared__ float wS[100][48];   // wS[k][g*12 + j], j<10
  int tid = threadIdx.x;
  int fg = tid & 3;     // 4 f-groups x 10
  int ng = tid >> 2;    // 64 node-groups x 4 consecutive nodes
  int n0 = blockIdx.x * 256;
  int fb = blockIdx.y;  // f-tile base fb*40

  // stage W tile once: 100k x 40f
  for (int idx = tid; idx < 4000; idx += 256){
    int k = idx / 40, f = idx - k*40;
    int g = f / 10, j = f - g*10;
    wS[k][g*12 + j] = W2[(size_t)k*200 + fb*40 + f];
  }

  float acc[4][10];
#pragma unroll
  for (int i=0;i<4;++i)
#pragma unroll
    for (int j=0;j<10;++j) acc[i][j]=0.f;

  for (int kc = 0; kc < 5; ++kc){
    int kt = kc*20;
    __syncthreads();   // kc=0: covers wS staging; else: aS readers done
    // stage A chunk transposed: a2[n0+n][kt+q*4..+3] -> aS[q*4+r][n]
#pragma unroll
    for (int c = 0; c < 5; ++c){
      int idx = c*256 + tid;            // [0,1280)
      int n = idx / 5, q = idx - n*5;   // n<256, q<5
      int gn = n0 + n;
      float4 v = make_float4(0.f,0.f,0.f,0.f);
      if (gn < N) v = *(const float4*)(a2 + (size_t)gn*100 + kt + q*4);
      aS[q*4+0][n] = v.x;
      aS[q*4+1][n] = v.y;
      aS[q*4+2][n] = v.z;
      aS[q*4+3][n] = v.w;
    }
    __syncthreads();
#pragma unroll
    for (int kl = 0; kl < 20; ++kl){
      float a[4], w[10];
      *(float4*)a = *(const float4*)&aS[kl][ng*4];
      const float* wr = &wS[kt+kl][fg*12];
      *(float4*)&w[0] = *(const float4*)&wr[0];
      *(float4*)&w[4] = *(const float4*)&wr[4];
      *(float2*)&w[8] = *(const float2*)&wr[8];
#pragma unroll
      for (int j=0;j<10;++j){
        float wv = w[j];
#pragma unroll
        for (int i=0;i<4;++i) acc[i][j] += a[i]*wv;
      }
    }
  }

  int fbase = fb*40 + fg*10;
  float bias[10];
#pragma unroll
  for (int j=0;j<10;++j) bias[j] = b2[fbase+j];
#pragma unroll
  for (int i=0;i<4;++i){
    int n = n0 + ng*4 + i;
    if (n < N){
      float* orow = h2s + (size_t)n*200 + fbase;
#pragma unroll
      for (int j=0;j<5;++j){
        float2 o;
        o.x = silu_f(acc[i][2*j+0] + bias[2*j+0]);
        o.y = silu_f(acc[i][2*j+1] + bias[2*j+1]);
        *(float2*)&orow[2*j] = o;
      }
    }
  }
}

// ---------- pool (mean over batch) + MLP head, one block per graph ----------
__global__ __launch_bounds__(256) void k_pool(const float* __restrict__ h2s, const int* __restrict__ batch,
                       const float* __restrict__ W3, const float* __restrict__ b3,
                       const float* __restrict__ W4, const float* __restrict__ b4,
                       float* __restrict__ out, int N){
  __shared__ float pl[200];
  __shared__ float h3[100];
  int g = blockIdx.x; int tid = threadIdx.x;
  // lower_bound(batch, g) and lower_bound(batch, g+1)
  int lo=0, hi=N;
  while (lo<hi){ int m=(lo+hi)>>1; if (batch[m] < g) lo=m+1; else hi=m; }
  int s = lo;
  hi=N;
  while (lo<hi){ int m=(lo+hi)>>1; if (batch[m] < g+1) lo=m+1; else hi=m; }
  int e = lo;
  float inv = (e>s) ? 1.0f/(float)(e-s) : 0.0f;
  if (tid < 200){
    float acc=0.f;
    for (int n=s; n<e; ++n) acc += h2s[(size_t)n*200 + tid];
    pl[tid] = acc*inv;
  }
  __syncthreads();
  if (tid < 100){
    float acc = b3[tid];
    for (int k=0;k<200;++k) acc += pl[k]*W3[k*100+tid];
    h3[tid] = silu_f(acc);
  }
  __syncthreads();
  if (tid < WF){
    float p = 0.f;
    if (tid < 100)      p  = h3[tid]     * W4[tid];
    if (tid + 64 < 100) p += h3[tid+64]  * W4[tid+64];
#pragma unroll
    for (int off=32; off; off>>=1) p += __shfl_down(p, off);
    if (tid==0) out[g] = p + b4[0];
  }
}

extern "C" void kernel_launch(void* const* d_in, const int* in_sizes, int n_in,
                              void* d_out, int out_size, void* d_ws, size_t ws_size,
                              hipStream_t stream){
  const float* x  = (const float*)d_in[0];
  const int*   ei = (const int*)  d_in[1];
  const int* batch= (const int*)  d_in[2];
  const float* W1 = (const float*)d_in[4];
  const float* b1 = (const float*)d_in[5];
  const float* W2 = (const float*)d_in[6];
  const float* b2 = (const float*)d_in[7];
  const float* W3 = (const float*)d_in[8];
  const float* b3 = (const float*)d_in[9];
  const float* W4 = (const float*)d_in[10];
  const float* b4 = (const float*)d_in[11];
  float* out = (float*)d_out;

  int N = in_sizes[0]/3;
  int E = in_sizes[1]/2;
  int G = out_size;
  const int* src = ei;
  const int* dst = ei + E;

  char* base = (char*)d_ws; size_t off = 0;
  auto alloc = [&](size_t bytes)->void*{
    void* p = base + off;
    off = (off + bytes + 255) & ~(size_t)255;
    return p;
  };
  int*   cnt      = (int*)  alloc((size_t)N*4);
  int*   rowstart = (int*)  alloc((size_t)(N+1)*4);
  int*   cursor   = (int*)  alloc((size_t)N*4);
  int*   bsum     = (int*)  alloc(4096);
  int*   colsrc   = (int*)  alloc((size_t)E*4);
  float* wedge    = (float*)alloc((size_t)E*4);
  float* dinv     = (float*)alloc((size_t)N*4);
  float* h1s      = (float*)alloc((size_t)N*100*4);
  float* a2       = (float*)alloc((size_t)N*100*4);
  float* h2s      = (float*)alloc((size_t)N*200*4);
  (void)ws_size; (void)n_in;

  hipMemsetAsync(cnt, 0, (size_t)N*4, stream);
  int gE = (E+255)/256;
  k_count<<<gE,256,0,stream>>>(dst, cnt, E);
  int nb = (N+2047)/2048;
  k_scan1<<<nb,256,0,stream>>>(cnt, rowstart, bsum, N);
  k_scan3<<<(N+255)/256,256,0,stream>>>(bsum, cnt, rowstart, cursor, dinv, N, E, nb);
  k_fill<<<gE,256,0,stream>>>(src, dst, dinv, cursor, colsrc, wedge, E);
  k_l1<<<(N+255)/256,256,0,stream>>>(x, rowstart, colsrc, wedge, dinv, W1, b1, h1s, N);
  k_agg2<<<(N+3)/4,256,0,stream>>>(h1s, rowstart, colsrc, wedge, dinv, a2, N);
  dim3 gmm((N+255)/256, 5);
  k_mm2<<<gmm,256,0,stream>>>(a2, W2, b2, h2s, N);
  k_pool<<<G,256,0,stream>>>(h2s, batch, W3, b3, W4, b4, out, N);
}